// Round 7
// baseline (658.041 us; speedup 1.0000x reference)
//
#include <hip/hip_runtime.h>
#include <cstdint>
#include <cstddef>

// ---------------- types ----------------
typedef __attribute__((ext_vector_type(8))) _Float16 half8;   // MFMA f16 A/B frag (4 VGPRs)
typedef __attribute__((ext_vector_type(4))) _Float16 half4;
typedef __attribute__((ext_vector_type(2))) __fp16   fp16x2;  // cvt_pkrtz result type
typedef __attribute__((ext_vector_type(4))) float    floatx4; // MFMA C/D frag

static constexpr int B_ROWS = 16384;
static constexpr int IN_DIM = 256;
static constexpr int H_DIM  = 512;
static constexpr int NB     = 16;

__device__ __forceinline__ float fast_tanh(float x) {
  float ax = fabsf(x);
  float e  = __expf(2.0f * ax);             // e >= 1, inf-safe
  float t  = 1.0f - 2.0f / (e + 1.0f);
  return copysignf(t, x);
}

// ---------------- prep: x column-stats partials (blocks 0..127) + coeff cvt (blocks 128+) ----
// cvt folds K_n = exp(-2 c_n^2) into the fp16 coeffs.
__global__ __launch_bounds__(256) void prep_k(const float* __restrict__ c1, _Float16* __restrict__ d1, size_t n41,
                                              const float* __restrict__ c2, _Float16* __restrict__ d2, size_t n42,
                                              const float* __restrict__ X,
                                              float* __restrict__ ps, float* __restrict__ ps2) {
  const int bx = blockIdx.x;
  if (bx < 128) {
    // ---- stats on X: cols=256 (4 col-groups of 64), 32 row-segs of 512 ----
    int c     = (bx & 3) * 64 + (threadIdx.x & 63);
    int chunk = threadIdx.x >> 6;
    int seg   = bx >> 2;
    int r0    = seg * 512;
    double s = 0.0, s2 = 0.0;
    for (int r = r0 + chunk; r < r0 + 512; r += 4) {
      float v = X[(size_t)r * IN_DIM + c];
      s += v; s2 += (double)v * (double)v;
    }
    __shared__ float Ls[256], Ls2[256];
    Ls[threadIdx.x] = (float)s; Ls2[threadIdx.x] = (float)s2;
    __syncthreads();
    if (chunk == 0) {
      int cl = threadIdx.x;
      float a  = Ls[cl]  + Ls[cl + 64]  + Ls[cl + 128]  + Ls[cl + 192];
      float b  = Ls2[cl] + Ls2[cl + 64] + Ls2[cl + 128] + Ls2[cl + 192];
      ps [(size_t)seg * IN_DIM + c] = a;
      ps2[(size_t)seg * IN_DIM + c] = b;
    }
  } else {
    // ---- coeff conversion, grid-stride over remaining blocks ----
    size_t tot = n41 + n42;
    int nb_blocks = gridDim.x - 128;
    for (size_t i = (size_t)(bx - 128) * 256 + threadIdx.x; i < tot;
         i += (size_t)nb_blocks * 256) {
      const float4* sp; half4* dp; size_t j;
      if (i < n41) { sp = (const float4*)c1; dp = (half4*)d1; j = i; }
      else         { sp = (const float4*)c2; dp = (half4*)d2; j = i - n41; }
      float4 v = sp[j];
      int nb = (int)((j << 2) & 15);
      half4 r;
      float e0 = -2.f + (float)(nb + 0) * (4.f / 15.f);
      float e1 = -2.f + (float)(nb + 1) * (4.f / 15.f);
      float e2 = -2.f + (float)(nb + 2) * (4.f / 15.f);
      float e3 = -2.f + (float)(nb + 3) * (4.f / 15.f);
      r[0] = (_Float16)(v.x * __expf(-2.f * e0 * e0));
      r[1] = (_Float16)(v.y * __expf(-2.f * e1 * e1));
      r[2] = (_Float16)(v.z * __expf(-2.f * e2 * e2));
      r[3] = (_Float16)(v.w * __expf(-2.f * e3 * e3));
      dp[j] = r;
    }
  }
}

// ---------------- stats finalize (float partials) — used only before layer 3 ----------------
// Emits isd = 1/(sd+eps) and nmi = -mu*isd so normalize is a single FMA downstream.
__global__ void stats_final_k(const float* __restrict__ ps,
                              const float* __restrict__ ps2,
                              int segs, int cols, int rows,
                              float* __restrict__ nmi, float* __restrict__ isd) {
  int c = blockIdx.x * blockDim.x + threadIdx.x;
  if (c >= cols) return;
  double s = 0.0, s2 = 0.0;
  for (int g = 0; g < segs; g++) { s += ps[(size_t)g * cols + c]; s2 += ps2[(size_t)g * cols + c]; }
  double mean = s / rows;
  double var  = (s2 - s * s / rows) / (rows - 1);   // ddof=1
  if (var < 0.0) var = 0.0;
  float sd = (float)sqrt(var);
  float iv = 1.0f / (sd + 1e-6f);
  isd[c] = iv;
  nmi[c] = -(float)mean * iv;
}

// ---------------- fused stats+normalize+expand+GEMM+tanh + column-stats partials ----------------
// H[b, o] = tanh( sum_k basis(xn[b, k/16])_[k%16] * Cb[o, k] ),  K = C*16
// 128x128 tile, BK=64, 512 threads (8 waves 2m x 4n), grid (128,4), 2 blocks/CU.
// R13: B DIRECT TO REGISTERS (no Bs LDS). R6 post-mortem: MFMA(36%) + VALU(37%) + LDS
// pipe (~18%) ~= 100% of wall -> the three pipes run SERIALLY (barrier convoy: all 4
// waves/SIMD do ds_reads together, then MFMA together, then expand together).
// Fix: B-frags are loaded global->reg, double-buffered (bfA/bfB named sets, rule #20),
// prefetched one step ahead. B loads are barrier-INDEPENDENT: raw lgkm-only barriers
// (no vmcnt drain -> prefetch rides across; __syncthreads would drain it). LDS work
// per step ~halves; post-barrier critical path = one ds_read (af) instead of DMA+12.
// B is L2-resident (8 MB); 2x L2 read traffic (~12 TB/s) << 34 TB/s ceiling.
// Also fused: per-layer column stats (isd,nmi) computed in the PROLOGUE from the
// producer's partial sums (saves 2 dispatches + gaps); SN[512] float2 table in LDS.
// A: K-major LDS, erow=tid&127 banking (R6: conflicts=0). Epilogue: tanh + col sums.
__global__ __launch_bounds__(512, 4) void kan_gemm_fused(const float* __restrict__ X,    // [B, C]
                                                         const float* __restrict__ psin, // [segs, C]
                                                         const float* __restrict__ ps2in,
                                                         int segs,
                                                         const _Float16* __restrict__ Bm, // [512, C*16]
                                                         float* __restrict__ Hout,        // [B, 512]
                                                         float* __restrict__ psum,        // [128, 512]
                                                         float* __restrict__ psum2,       // [128, 512]
                                                         int C) {
  const int K = C << 4;
  const int steps = K >> 6;                 // BK = 64; steps even (64 or 128)
  __shared__ __align__(16) _Float16 As[2][128 * 64];   // 32 KB; chunk = kseg*128 + row
  __shared__ float2 SN[512];                           //  4 KB; (isd, -mu*isd) per col
  const int tid  = threadIdx.x;
  const int w = tid >> 6, lane = tid & 63;
  const int wm = w & 1, wn = w >> 1;        // 2x4 wave grid: wave owns 64 rows x 32 cols
  const int lrow = lane & 15, quad = lane >> 4;
  const int row0 = blockIdx.x * 128;
  const int col0 = blockIdx.y * 128;

  // ---- per-lane B fragment pointer: lane needs Bm[col0+wn*32+t*16+lrow][k*64+ks*32+quad*8]
  const _Float16* gBf = Bm + (size_t)(col0 + wn * 32 + lrow) * K + quad * 8;

  // ---- A expansion: erow = tid&127 (consecutive lanes -> consecutive rows, conflict-free
  //      b128 writes), eh = tid>>7 (wave-uniform col slot 0..3). Step k: col 4k+eh.
  const int erow = tid & 127;
  const int eh   = tid >> 7;
  const float* xp = X + (size_t)(row0 + erow) * C + eh;   // step k: xp[4k]

  floatx4 acc[4][2] = {};
  half8 bfA[4], bfB[4];                     // named double-buffer (static indexing)

  auto loadB = [&](int k, half8 (&bf)[4]) {
#pragma unroll
    for (int ks = 0; ks < 2; ks++)
#pragma unroll
      for (int t = 0; t < 2; t++)
        bf[ks * 2 + t] = *(const half8*)(gBf + (size_t)t * 16 * K + (size_t)k * 64 + ks * 32);
  };

  // packed expansion: h[n] = Wv * g^n; f32 anchors at n=0,8; packed-f16 *g^2 chain between.
  auto expand_store = [&](float xr, float2 sn, int bufi) {
    float xn = fminf(fmaxf(fmaf(xr, sn.x, sn.y), -3.f), 3.f);
    float Wv = __expf(fmaf(-2.f, xn, -8.f) * xn);
    float g  = __expf((16.f / 15.f) * xn);
    float g2 = g * g, g4 = g2 * g2, g8 = g4 * g4;
    fp16x2 gg = __builtin_amdgcn_cvt_pkrtz(g2, g2);
    union { fp16x2 q[4]; half8 v8; } u0, u1;
    u0.q[0] = __builtin_amdgcn_cvt_pkrtz(Wv, Wv * g);
    u0.q[1] = u0.q[0] * gg;
    u0.q[2] = u0.q[1] * gg;
    u0.q[3] = u0.q[2] * gg;
    float W8 = Wv * g8;
    u1.q[0] = __builtin_amdgcn_cvt_pkrtz(W8, W8 * g);
    u1.q[1] = u1.q[0] * gg;
    u1.q[2] = u1.q[1] * gg;
    u1.q[3] = u1.q[2] * gg;
    int ks0 = 2 * eh;
    *(half8*)&As[bufi][(size_t)(ks0 * 128 + erow) * 8]       = u0.v8;
    *(half8*)&As[bufi][(size_t)((ks0 + 1) * 128 + erow) * 8] = u1.v8;
  };

  auto mfma_half = [&](const half8 (&bf)[4], int ks, int abuf_) {
    half8 af[4];
#pragma unroll
    for (int t = 0; t < 4; t++) {
      int arow = wm * 64 + t * 16 + lrow;
      af[t] = *(const half8*)&As[abuf_][(size_t)((ks * 4 + quad) * 128 + arow) * 8];
    }
    __builtin_amdgcn_s_setprio(1);
#pragma unroll
    for (int tm = 0; tm < 4; tm++)
#pragma unroll
      for (int tn = 0; tn < 2; tn++)
        acc[tm][tn] = __builtin_amdgcn_mfma_f32_16x16x32_f16(af[tm], bf[ks * 2 + tn], acc[tm][tn], 0, 0, 0);
    __builtin_amdgcn_s_setprio(0);
  };

  // ---- prologue: B(0) in flight under the fused stats pass ----
  loadB(0, bfA);
  for (int c = tid; c < C; c += 512) {
    double s = 0.0, s2 = 0.0;
    for (int g = 0; g < segs; g++) {
      s  += psin [(size_t)g * C + c];
      s2 += ps2in[(size_t)g * C + c];
    }
    double mean = s / B_ROWS;
    double var  = (s2 - s * s / B_ROWS) / (B_ROWS - 1);   // ddof=1
    if (var < 0.0) var = 0.0;
    float iv = 1.0f / ((float)sqrt(var) + 1e-6f);
    SN[c] = make_float2(iv, -(float)mean * iv);
  }
  float x0 = xp[0];
  asm volatile("s_waitcnt lgkmcnt(0)" ::: "memory");
  __builtin_amdgcn_s_barrier();
  __builtin_amdgcn_sched_barrier(0);
  float2 sn0 = SN[eh];
  float xv   = xp[4];
  float2 snv = SN[4 + eh];
  expand_store(x0, sn0, 0);
  asm volatile("s_waitcnt lgkmcnt(0)" ::: "memory");
  __builtin_amdgcn_s_barrier();
  __builtin_amdgcn_sched_barrier(0);

  // ---- main loop (x2 unrolled): lgkm-only barriers; B prefetch rides vmcnt across ----
  for (int k = 0; k < steps; k += 2) {
    // even step k: As[0] + bfA; prefetch bfB(k+1); expand(k+1)->As[1]
    loadB(k + 1, bfB);
    mfma_half(bfA, 0, 0);
    expand_store(xv, snv, 1);
    if (k + 2 < steps) { xv = xp[4 * (k + 2)]; snv = SN[4 * (k + 2) + eh]; }
    mfma_half(bfA, 1, 0);
    asm volatile("s_waitcnt lgkmcnt(0)" ::: "memory");
    __builtin_amdgcn_s_barrier();
    __builtin_amdgcn_sched_barrier(0);
    // odd step k+1: As[1] + bfB; prefetch bfA(k+2); expand(k+2)->As[0]
    if (k + 2 < steps) loadB(k + 2, bfA);
    mfma_half(bfB, 0, 1);
    if (k + 2 < steps) {
      expand_store(xv, snv, 0);
      if (k + 3 < steps) { xv = xp[4 * (k + 3)]; snv = SN[4 * (k + 3) + eh]; }
    }
    mfma_half(bfB, 1, 1);
    asm volatile("s_waitcnt lgkmcnt(0)" ::: "memory");
    __builtin_amdgcn_s_barrier();
    __builtin_amdgcn_sched_barrier(0);
  }

  // ---- epilogue: C/D layout col=lane&15, row=quad*4+reg; fused tanh + column partial sums ----
  // reduction buffers alias As (dead after the loop's final barrier)
  float* Rs1 = reinterpret_cast<float*>(&As[0][0]);   // [2][128]
  float* Rs2 = Rs1 + 256;                              // [2][128]
  float s1[2] = {0.f, 0.f}, s2v[2] = {0.f, 0.f};
#pragma unroll
  for (int tm = 0; tm < 4; tm++) {
#pragma unroll
    for (int tn = 0; tn < 2; tn++) {
      int gcol = col0 + wn * 32 + tn * 16 + lrow;
#pragma unroll
      for (int r = 0; r < 4; r++) {
        int grow = row0 + wm * 64 + tm * 16 + quad * 4 + r;
        float v = fast_tanh(acc[tm][tn][r]);
        Hout[(size_t)grow * H_DIM + gcol] = v;
        s1[tn] += v; s2v[tn] += v * v;
      }
    }
  }
#pragma unroll
  for (int tn = 0; tn < 2; tn++) {
    s1[tn]  += __shfl_xor(s1[tn], 16);  s1[tn]  += __shfl_xor(s1[tn], 32);
    s2v[tn] += __shfl_xor(s2v[tn], 16); s2v[tn] += __shfl_xor(s2v[tn], 32);
  }
  if (quad == 0) {
#pragma unroll
    for (int tn = 0; tn < 2; tn++) {
      Rs1[wm * 128 + wn * 32 + tn * 16 + lrow] = s1[tn];
      Rs2[wm * 128 + wn * 32 + tn * 16 + lrow] = s2v[tn];
    }
  }
  asm volatile("s_waitcnt lgkmcnt(0)" ::: "memory");    // avoid draining Hout stores
  __builtin_amdgcn_s_barrier();
  __builtin_amdgcn_sched_barrier(0);
  if (tid < 128) {
    psum [(size_t)blockIdx.x * H_DIM + col0 + tid] = Rs1[tid] + Rs1[128 + tid];
    psum2[(size_t)blockIdx.x * H_DIM + col0 + tid] = Rs2[tid] + Rs2[128 + tid];
  }
}

// ---------------- layer 3 (out dim 1) + skip, fp32, normalize fused ----------------
__global__ __launch_bounds__(256) void layer3_k(const float* __restrict__ H2,
                                                const float* __restrict__ nmi,
                                                const float* __restrict__ isd,
                                                const float* __restrict__ C3,
                                                const float* __restrict__ X,
                                                const float* __restrict__ SW,
                                                const float* __restrict__ SB,
                                                float* __restrict__ OUT) {
  int w = threadIdx.x >> 6, lane = threadIdx.x & 63;
  float Kn[NB];
#pragma unroll
  for (int n = 0; n < NB; n++) {
    float c = -2.f + (float)n * (4.f / 15.f);
    Kn[n] = __expf(-2.f * c * c);
  }
  float sb0 = SB[0];
  int row_base = blockIdx.x * 16 + w * 4;
  for (int r = 0; r < 4; r++) {
    int row = row_base + r;
    float s = 0.f;
#pragma unroll
    for (int j = 0; j < 8; j++) {
      int i = lane + 64 * j;
      float hv = H2[(size_t)row * H_DIM + i];
      float xn = fminf(fmaxf(fmaf(hv, isd[i], nmi[i]), -3.f), 3.f);
      float Wf = __expf(fmaf(-2.f, xn, -8.f) * xn);
      float gf = __expf((16.f / 15.f) * xn);
      const floatx4* cp = (const floatx4*)(C3 + (size_t)i * NB);
      floatx4 c0 = cp[0], c1 = cp[1], c2 = cp[2], c3 = cp[3];
      float p = Wf;
#pragma unroll
      for (int n = 0; n < 4; n++) { s += p * Kn[n]      * c0[n]; p *= gf; }
#pragma unroll
      for (int n = 0; n < 4; n++) { s += p * Kn[n + 4]  * c1[n]; p *= gf; }
#pragma unroll
      for (int n = 0; n < 4; n++) { s += p * Kn[n + 8]  * c2[n]; p *= gf; }
#pragma unroll
      for (int n = 0; n < 4; n++) { s += p * Kn[n + 12] * c3[n]; p *= gf; }
    }
#pragma unroll
    for (int j = 0; j < 4; j++) {
      int i = lane + 64 * j;
      s += X[(size_t)row * IN_DIM + i] * SW[i];
    }
#pragma unroll
    for (int off = 32; off > 0; off >>= 1) s += __shfl_down(s, off);
    if (lane == 0) OUT[row] = s + sb0;
  }
}

// ---------------- launcher ----------------
extern "C" void kernel_launch(void* const* d_in, const int* in_sizes, int n_in,
                              void* d_out, int out_size, void* d_ws, size_t ws_size,
                              hipStream_t stream) {
  const float* x  = (const float*)d_in[0];   // [16384, 256]
  const float* c1 = (const float*)d_in[1];   // [512, 256, 16]
  const float* c2 = (const float*)d_in[2];   // [512, 512, 16]
  const float* c3 = (const float*)d_in[3];   // [1, 512, 16]
  const float* sw = (const float*)d_in[4];   // [1, 256]
  const float* sb = (const float*)d_in[5];   // [1]
  float* out = (float*)d_out;

  const int B = B_ROWS, IN = IN_DIM, H = H_DIM;

  char* ws = (char*)d_ws;
  size_t off = 0;
  auto alloc = [&](size_t bytes) -> void* {
    void* p = ws + off;
    off += (bytes + 255) & ~(size_t)255;
    return p;
  };
  _Float16* C1h = (_Float16*)alloc((size_t)H * IN * NB * 2);  //  4 MB
  _Float16* C2h = (_Float16*)alloc((size_t)H * H  * NB * 2);  //  8 MB
  float* H1 = (float*)alloc((size_t)B * H * 4);               // 32 MB
  float* H2 = (float*)alloc((size_t)B * H * 4);               // 32 MB
  // separate partial buffers per producer (consumer kernels read them in their prologue;
  // reusing one buffer would race: a fast block's epilogue write vs a slow block's read)
  float* psX  = (float*)alloc(32 * 256 * 4);                  // prep out (x stats)
  float* ps2X = (float*)alloc(32 * 256 * 4);
  float* psA  = (float*)alloc(128 * 512 * 4);                 // G1 out (H1 stats)
  float* ps2A = (float*)alloc(128 * 512 * 4);
  float* psB  = (float*)alloc(128 * 512 * 4);                 // G2 out (H2 stats)
  float* ps2B = (float*)alloc(128 * 512 * 4);
  float* nmi = (float*)alloc(512 * 4);
  float* isd = (float*)alloc(512 * 4);

  // ---- prep: x-stats partials + coeff cvt in one dispatch ----
  prep_k<<<128 + 1024, 256, 0, stream>>>(c1, C1h, (size_t)H * IN * NB / 4,
                                         c2, C2h, (size_t)H * H * NB / 4,
                                         x, psX, ps2X);

  // ---- layer 1 (C=256, K=4096); stats fused in prologue; epilogue emits H1 partials ----
  kan_gemm_fused<<<dim3(B / 128, 4), 512, 0, stream>>>(x, psX, ps2X, 32, C1h, H1, psA, ps2A, IN);

  // ---- layer 2 (C=512, K=8192); stats fused; epilogue emits H2 partials ----
  kan_gemm_fused<<<dim3(B / 128, 4), 512, 0, stream>>>(H1, psA, ps2A, 128, C2h, H2, psB, ps2B, H);

  // ---- layer 3 + skip (H2 stats via stats_final, normalize fused) ----
  stats_final_k<<<2, 256, 0, stream>>>(psB, ps2B, 128, H, B, nmi, isd);
  layer3_k<<<B / 16, 256, 0, stream>>>(H2, nmi, isd, c3, x, sw, sb, out);
}

// Round 9
// 457.332 us; speedup vs baseline: 1.4389x; 1.4389x over previous
//
#include <hip/hip_runtime.h>
#include <cstdint>
#include <cstddef>

// ---------------- types ----------------
typedef __attribute__((ext_vector_type(8))) _Float16 half8;   // MFMA f16 A/B frag (4 VGPRs)
typedef __attribute__((ext_vector_type(4))) _Float16 half4;
typedef __attribute__((ext_vector_type(2))) __fp16   fp16x2;  // cvt_pkrtz result type
typedef __attribute__((ext_vector_type(4))) float    floatx4; // MFMA C/D frag

static constexpr int B_ROWS = 16384;
static constexpr int IN_DIM = 256;
static constexpr int H_DIM  = 512;
static constexpr int NB     = 16;

__device__ __forceinline__ float fast_tanh(float x) {
  float ax = fabsf(x);
  float e  = __expf(2.0f * ax);             // e >= 1, inf-safe
  float t  = 1.0f - 2.0f / (e + 1.0f);
  return copysignf(t, x);
}

// async global->LDS, 16B per lane; LDS dest must be wave-uniform base + lane*16
__device__ __forceinline__ void gld16(const void* g, void* l) {
  __builtin_amdgcn_global_load_lds(
      (const __attribute__((address_space(1))) unsigned int*)g,
      (__attribute__((address_space(3))) unsigned int*)l, 16, 0, 0);
}

// ---------------- prep: x column-stats partials (blocks 0..127) + coeff cvt (blocks 128+) ----
// cvt folds K_n = exp(-2 c_n^2) into the fp16 coeffs.
__global__ __launch_bounds__(256) void prep_k(const float* __restrict__ c1, _Float16* __restrict__ d1, size_t n41,
                                              const float* __restrict__ c2, _Float16* __restrict__ d2, size_t n42,
                                              const float* __restrict__ X,
                                              float* __restrict__ ps, float* __restrict__ ps2) {
  const int bx = blockIdx.x;
  if (bx < 128) {
    // ---- stats on X: cols=256 (4 col-groups of 64), 32 row-segs of 512 ----
    int c     = (bx & 3) * 64 + (threadIdx.x & 63);
    int chunk = threadIdx.x >> 6;
    int seg   = bx >> 2;
    int r0    = seg * 512;
    double s = 0.0, s2 = 0.0;
    for (int r = r0 + chunk; r < r0 + 512; r += 4) {
      float v = X[(size_t)r * IN_DIM + c];
      s += v; s2 += (double)v * (double)v;
    }
    __shared__ float Ls[256], Ls2[256];
    Ls[threadIdx.x] = (float)s; Ls2[threadIdx.x] = (float)s2;
    __syncthreads();
    if (chunk == 0) {
      int cl = threadIdx.x;
      float a  = Ls[cl]  + Ls[cl + 64]  + Ls[cl + 128]  + Ls[cl + 192];
      float b  = Ls2[cl] + Ls2[cl + 64] + Ls2[cl + 128] + Ls2[cl + 192];
      ps [(size_t)seg * IN_DIM + c] = a;
      ps2[(size_t)seg * IN_DIM + c] = b;
    }
  } else {
    // ---- coeff conversion, grid-stride over remaining blocks ----
    size_t tot = n41 + n42;
    int nb_blocks = gridDim.x - 128;
    for (size_t i = (size_t)(bx - 128) * 256 + threadIdx.x; i < tot;
         i += (size_t)nb_blocks * 256) {
      const float4* sp; half4* dp; size_t j;
      if (i < n41) { sp = (const float4*)c1; dp = (half4*)d1; j = i; }
      else         { sp = (const float4*)c2; dp = (half4*)d2; j = i - n41; }
      float4 v = sp[j];
      int nb = (int)((j << 2) & 15);
      half4 r;
      float e0 = -2.f + (float)(nb + 0) * (4.f / 15.f);
      float e1 = -2.f + (float)(nb + 1) * (4.f / 15.f);
      float e2 = -2.f + (float)(nb + 2) * (4.f / 15.f);
      float e3 = -2.f + (float)(nb + 3) * (4.f / 15.f);
      r[0] = (_Float16)(v.x * __expf(-2.f * e0 * e0));
      r[1] = (_Float16)(v.y * __expf(-2.f * e1 * e1));
      r[2] = (_Float16)(v.z * __expf(-2.f * e2 * e2));
      r[3] = (_Float16)(v.w * __expf(-2.f * e3 * e3));
      dp[j] = r;
    }
  }
}

// ---------------- stats finalize (float partials) ----------------
// Emits isd = 1/(sd+eps) and nmi = -mu*isd so normalize is a single FMA downstream.
__global__ void stats_final_k(const float* __restrict__ ps,
                              const float* __restrict__ ps2,
                              int segs, int cols, int rows,
                              float* __restrict__ nmi, float* __restrict__ isd) {
  int c = blockIdx.x * blockDim.x + threadIdx.x;
  if (c >= cols) return;
  double s = 0.0, s2 = 0.0;
  for (int g = 0; g < segs; g++) { s += ps[(size_t)g * cols + c]; s2 += ps2[(size_t)g * cols + c]; }
  double mean = s / rows;
  double var  = (s2 - s * s / rows) / (rows - 1);   // ddof=1
  if (var < 0.0) var = 0.0;
  float sd = (float)sqrt(var);
  float iv = 1.0f / (sd + 1e-6f);
  isd[c] = iv;
  nmi[c] = -(float)mean * iv;
}

// ---------------- fused normalize+expand+GEMM+tanh + column-stats partials ----------------
// H[b, o] = tanh( sum_k basis(xn[b, k/16])_[k%16] * Cb[o, k] ),  K = C*16
// 128x128 tile, BK=64, 512 threads, grid (128,4), 2 blocks/CU.
// R15 = R14 (k-split wave grid) with the LDS-aliasing bug fixed: R14's merge wrote
// through (float*)&As[0][0] up to 66 KB — UB across separate __shared__ objects
// (tiles p>=2 and Rs landed outside As; absmax 11.3). Fix: ONE __shared__ 80 KB byte
// array, As/Bs/merge/Rs pointers carved out manually -> aliasing is well-defined.
// R14 design (unchanged): 8 waves = 2m x 2n x 2k; wave owns a 64x64 output over HALF
// of BK (kq = ksw*4+quad). Reads/wave/step: 4 af + 4 bf = 8 (vs 12 at 64x32) -> LDS
// wave-instr per CU per step 256 -> 192 (R6 step time ~= 256 x 12 cyc -> bound 2304).
// K-split pairs (w, w+4) merge via LDS at the end: ks=1 dumps 16KB tile, ks=0 adds +
// does tanh/store/colsum epilogue. One-time cost vs 128 steps of savings.
// Kept: DMA tri-buffer + counted vmcnt (no in-loop vmcnt drain; expand(k+1)'s x-reg
// consumption retires DMA(k+1) via in-order vmcnt), erow=tid&127 A-write banking
// (conflicts=0, R6-measured), packed expansion, lgkm-only raw barriers.
__global__ __launch_bounds__(512, 4) void kan_gemm_fused(const float* __restrict__ X,   // [B, C]
                                                         const float* __restrict__ nmi,
                                                         const float* __restrict__ isd,
                                                         const _Float16* __restrict__ Bm, // [512, C*16]
                                                         float* __restrict__ Hout,        // [B, 512]
                                                         float* __restrict__ psum,        // [128, 512]
                                                         float* __restrict__ psum2,       // [128, 512]
                                                         int C) {
  const int K = C << 4;
  const int steps = K >> 6;                 // BK = 64
  // ---- single LDS arena: [0,32K) = As (2 bufs), [32K,80K) = Bs (3 bufs);
  //      epilogue reuses [0,64K) as merge tiles + [64K,66K) as Rs. Well-defined.
  __shared__ __align__(16) unsigned char LDSB[81920];
  _Float16* const Asb = reinterpret_cast<_Float16*>(LDSB);           // 2 x 8192 halfs
  _Float16* const Bsb = reinterpret_cast<_Float16*>(LDSB + 32768);   // 3 x 8192 halfs
  const int tid  = threadIdx.x;
  const int w = tid >> 6, lane = tid & 63;
  const int wm = w & 1, wn = (w >> 1) & 1, ksw = w >> 2;  // 2x2 spatial, 2-way k-split
  const int lrow = lane & 15, quad = lane >> 4;
  const int row0 = blockIdx.x * 128;
  const int col0 = blockIdx.y * 128;
  const int kq = ksw * 4 + quad;            // this lane's kseg within BK=64

  // ---- B staging: buffer = 1024 chunks of 16B; thread owns chunks tid, tid+512.
  const int s_row = tid >> 3;               // 0..63
  const int s_sl  = tid & 7;
  const int s_seg = s_sl ^ ((s_row >> 1) & 7);
  const _Float16* gB = Bm + (size_t)(col0 + s_row) * K + s_seg * 8;

  // ---- A expansion: erow = tid&127 (consecutive lanes -> consecutive rows, conflict-free
  //      b128 writes), eh = tid>>7 (wave-uniform col slot 0..3). Step k: col 4k+eh.
  const int erow = tid & 127;
  const int eh   = tid >> 7;
  const float* xp  = X   + (size_t)(row0 + erow) * C + eh;  // step k: xp[4k]
  const float* mup = nmi + eh;
  const float* isp = isd + eh;

  floatx4 acc[4][4] = {};

  // packed expansion: h[n] = Wv * g^n; f32 anchors at n=0,8; packed-f16 *g^2 chain between.
  auto expand_store = [&](float xr, float ii, float bb, int bufi) {
    float xn = fminf(fmaxf(fmaf(xr, ii, bb), -3.f), 3.f);
    float Wv = __expf(fmaf(-2.f, xn, -8.f) * xn);
    float g  = __expf((16.f / 15.f) * xn);
    float g2 = g * g, g4 = g2 * g2, g8 = g4 * g4;
    fp16x2 gg = __builtin_amdgcn_cvt_pkrtz(g2, g2);
    union { fp16x2 q[4]; half8 v8; } u0, u1;
    u0.q[0] = __builtin_amdgcn_cvt_pkrtz(Wv, Wv * g);
    u0.q[1] = u0.q[0] * gg;
    u0.q[2] = u0.q[1] * gg;
    u0.q[3] = u0.q[2] * gg;
    float W8 = Wv * g8;
    u1.q[0] = __builtin_amdgcn_cvt_pkrtz(W8, W8 * g);
    u1.q[1] = u1.q[0] * gg;
    u1.q[2] = u1.q[1] * gg;
    u1.q[3] = u1.q[2] * gg;
    int ks0 = 2 * eh;
    *(half8*)&Asb[(size_t)bufi * 8192 + (size_t)(ks0 * 128 + erow) * 8]       = u0.v8;
    *(half8*)&Asb[(size_t)bufi * 8192 + (size_t)((ks0 + 1) * 128 + erow) * 8] = u1.v8;
  };

  // ---- prologue: DMA(0), DMA(1), expand(0); one-time vmcnt(0) drain ----
  float x0 = xp[0];
  float a0 = isp[0];
  float b0 = mup[0];
  gld16(gB, &Bsb[(size_t)tid * 8]);
  gld16(gB + (size_t)64 * K, &Bsb[(size_t)(tid + 512) * 8]);
  __builtin_amdgcn_sched_barrier(0);
  gld16(gB + 64, &Bsb[8192 + (size_t)tid * 8]);
  gld16(gB + 64 + (size_t)64 * K, &Bsb[8192 + (size_t)(tid + 512) * 8]);
  __builtin_amdgcn_sched_barrier(0);
  float xv = xp[4];                          // regs for step-0's expand(1)
  float av = isp[4];
  float bv = mup[4];
  expand_store(x0, a0, b0, 0);
  asm volatile("s_waitcnt vmcnt(0)" ::: "memory");   // one-time: Bs[0], Bs[1] resident
  asm volatile("s_waitcnt lgkmcnt(0)" ::: "memory");
  __builtin_amdgcn_s_barrier();
  __builtin_amdgcn_sched_barrier(0);

  // ---- main loop: raw barrier per step, vmcnt never drained ----
  int bcur = 0;                                      // Bs buffer for step k
  for (int k = 0; k < steps; k++) {
    const int abuf = k & 1;
    const bool more  = (k + 1 < steps);
    const bool more2 = (k + 2 < steps);
    const int b2 = (bcur == 0) ? 2 : bcur - 1;       // (k+2)%3
    if (more2) {
      gld16(gB + (size_t)(k + 2) * 64, &Bsb[(size_t)b2 * 8192 + (size_t)tid * 8]);
      gld16(gB + (size_t)(k + 2) * 64 + (size_t)64 * K,
            &Bsb[(size_t)b2 * 8192 + (size_t)(tid + 512) * 8]);
      __builtin_amdgcn_sched_barrier(0);
    }
    // frags: 4 A (tm) + 4 B (tn), each lane's kseg = kq
    half8 af[4], bf[4];
#pragma unroll
    for (int t = 0; t < 4; t++) {
      int arow = wm * 64 + t * 16 + lrow;
      af[t] = *(const half8*)&Asb[(size_t)abuf * 8192 + (size_t)(kq * 128 + arow) * 8];
    }
#pragma unroll
    for (int t = 0; t < 4; t++) {
      int brow = wn * 64 + t * 16 + lrow;
      int bchunk = brow * 8 + (kq ^ ((brow >> 1) & 7));
      bf[t] = *(const half8*)&Bsb[(size_t)bcur * 8192 + (size_t)bchunk * 8];
    }
    // MFMA first half (tm 0,1)
    __builtin_amdgcn_s_setprio(1);
#pragma unroll
    for (int tm = 0; tm < 2; tm++)
#pragma unroll
      for (int tn = 0; tn < 4; tn++)
        acc[tm][tn] = __builtin_amdgcn_mfma_f32_16x16x32_f16(af[tm], bf[tn], acc[tm][tn], 0, 0, 0);
    __builtin_amdgcn_s_setprio(0);
    // staging VALU between the MFMA halves; xv consumption retires DMA(k+1) (vmcnt order)
    if (more) {
      expand_store(xv, av, bv, abuf ^ 1);
      if (more2) {
        xv = xp[4 * (k + 2)];
        av = isp[4 * (k + 2)];
        bv = mup[4 * (k + 2)];
      }
    }
    // MFMA second half (tm 2,3)
    __builtin_amdgcn_s_setprio(1);
#pragma unroll
    for (int tm = 2; tm < 4; tm++)
#pragma unroll
      for (int tn = 0; tn < 4; tn++)
        acc[tm][tn] = __builtin_amdgcn_mfma_f32_16x16x32_f16(af[tm], bf[tn], acc[tm][tn], 0, 0, 0);
    __builtin_amdgcn_s_setprio(0);
    asm volatile("s_waitcnt lgkmcnt(0)" ::: "memory");   // LDS writes visible; NO vmcnt drain
    __builtin_amdgcn_s_barrier();
    __builtin_amdgcn_sched_barrier(0);
    bcur = (bcur == 2) ? 0 : bcur + 1;
  }

  // ---- k-split merge: ks=1 waves dump acc into the (dead) LDS arena; ks=0 adds ----
  float* MB = reinterpret_cast<float*>(LDSB);        // [0,64K): 4 tiles x 16 KB
  const int p = wm * 2 + wn;                         // spatial tile id 0..3
  asm volatile("s_waitcnt vmcnt(0)" ::: "memory");   // safety: all DMA landed (one-time)
  if (ksw == 1) {
    float* dst = MB + (size_t)p * 4096;
#pragma unroll
    for (int tm = 0; tm < 4; tm++)
#pragma unroll
      for (int tn = 0; tn < 4; tn++)
        *(floatx4*)&dst[((tm * 4 + tn) * 64 + lane) * 4] = acc[tm][tn];
  }
  asm volatile("s_waitcnt lgkmcnt(0)" ::: "memory");
  __builtin_amdgcn_s_barrier();
  __builtin_amdgcn_sched_barrier(0);

  // ---- epilogue on ks=0 waves: merge + tanh + store + column partial sums ----
  float* Rs1 = MB + 16384;                           // [64K,66K): [2][128] + [2][128]
  float* Rs2 = Rs1 + 256;
  if (ksw == 0) {
    const float* src = MB + (size_t)p * 4096;
    float s1[4] = {0.f, 0.f, 0.f, 0.f}, s2v[4] = {0.f, 0.f, 0.f, 0.f};
#pragma unroll
    for (int tm = 0; tm < 4; tm++) {
#pragma unroll
      for (int tn = 0; tn < 4; tn++) {
        floatx4 other = *(const floatx4*)&src[((tm * 4 + tn) * 64 + lane) * 4];
        int gcol = col0 + wn * 64 + tn * 16 + lrow;
#pragma unroll
        for (int r = 0; r < 4; r++) {
          int grow = row0 + wm * 64 + tm * 16 + quad * 4 + r;
          float v = fast_tanh(acc[tm][tn][r] + other[r]);
          Hout[(size_t)grow * H_DIM + gcol] = v;
          s1[tn] += v; s2v[tn] += v * v;
        }
      }
    }
#pragma unroll
    for (int tn = 0; tn < 4; tn++) {
      s1[tn]  += __shfl_xor(s1[tn], 16);  s1[tn]  += __shfl_xor(s1[tn], 32);
      s2v[tn] += __shfl_xor(s2v[tn], 16); s2v[tn] += __shfl_xor(s2v[tn], 32);
    }
    if (quad == 0) {
#pragma unroll
      for (int tn = 0; tn < 4; tn++) {
        Rs1[wm * 128 + wn * 64 + tn * 16 + lrow] = s1[tn];
        Rs2[wm * 128 + wn * 64 + tn * 16 + lrow] = s2v[tn];
      }
    }
  }
  asm volatile("s_waitcnt lgkmcnt(0)" ::: "memory");    // avoid draining Hout stores
  __builtin_amdgcn_s_barrier();
  __builtin_amdgcn_sched_barrier(0);
  if (tid < 128) {
    psum [(size_t)blockIdx.x * H_DIM + col0 + tid] = Rs1[tid] + Rs1[128 + tid];
    psum2[(size_t)blockIdx.x * H_DIM + col0 + tid] = Rs2[tid] + Rs2[128 + tid];
  }
}

// ---------------- layer 3 (out dim 1) + skip, fp32, normalize fused ----------------
__global__ __launch_bounds__(256) void layer3_k(const float* __restrict__ H2,
                                                const float* __restrict__ nmi,
                                                const float* __restrict__ isd,
                                                const float* __restrict__ C3,
                                                const float* __restrict__ X,
                                                const float* __restrict__ SW,
                                                const float* __restrict__ SB,
                                                float* __restrict__ OUT) {
  int w = threadIdx.x >> 6, lane = threadIdx.x & 63;
  float Kn[NB];
#pragma unroll
  for (int n = 0; n < NB; n++) {
    float c = -2.f + (float)n * (4.f / 15.f);
    Kn[n] = __expf(-2.f * c * c);
  }
  float sb0 = SB[0];
  int row_base = blockIdx.x * 16 + w * 4;
  for (int r = 0; r < 4; r++) {
    int row = row_base + r;
    float s = 0.f;
#pragma unroll
    for (int j = 0; j < 8; j++) {
      int i = lane + 64 * j;
      float hv = H2[(size_t)row * H_DIM + i];
      float xn = fminf(fmaxf(fmaf(hv, isd[i], nmi[i]), -3.f), 3.f);
      float Wf = __expf(fmaf(-2.f, xn, -8.f) * xn);
      float gf = __expf((16.f / 15.f) * xn);
      const floatx4* cp = (const floatx4*)(C3 + (size_t)i * NB);
      floatx4 c0 = cp[0], c1 = cp[1], c2 = cp[2], c3 = cp[3];
      float p = Wf;
#pragma unroll
      for (int n = 0; n < 4; n++) { s += p * Kn[n]      * c0[n]; p *= gf; }
#pragma unroll
      for (int n = 0; n < 4; n++) { s += p * Kn[n + 4]  * c1[n]; p *= gf; }
#pragma unroll
      for (int n = 0; n < 4; n++) { s += p * Kn[n + 8]  * c2[n]; p *= gf; }
#pragma unroll
      for (int n = 0; n < 4; n++) { s += p * Kn[n + 12] * c3[n]; p *= gf; }
    }
#pragma unroll
    for (int j = 0; j < 4; j++) {
      int i = lane + 64 * j;
      s += X[(size_t)row * IN_DIM + i] * SW[i];
    }
#pragma unroll
    for (int off = 32; off > 0; off >>= 1) s += __shfl_down(s, off);
    if (lane == 0) OUT[row] = s + sb0;
  }
}

// ---------------- launcher ----------------
extern "C" void kernel_launch(void* const* d_in, const int* in_sizes, int n_in,
                              void* d_out, int out_size, void* d_ws, size_t ws_size,
                              hipStream_t stream) {
  const float* x  = (const float*)d_in[0];   // [16384, 256]
  const float* c1 = (const float*)d_in[1];   // [512, 256, 16]
  const float* c2 = (const float*)d_in[2];   // [512, 512, 16]
  const float* c3 = (const float*)d_in[3];   // [1, 512, 16]
  const float* sw = (const float*)d_in[4];   // [1, 256]
  const float* sb = (const float*)d_in[5];   // [1]
  float* out = (float*)d_out;

  const int B = B_ROWS, IN = IN_DIM, H = H_DIM;

  char* ws = (char*)d_ws;
  size_t off = 0;
  auto alloc = [&](size_t bytes) -> void* {
    void* p = ws + off;
    off += (bytes + 255) & ~(size_t)255;
    return p;
  };
  _Float16* C1h = (_Float16*)alloc((size_t)H * IN * NB * 2);  //  4 MB
  _Float16* C2h = (_Float16*)alloc((size_t)H * H  * NB * 2);  //  8 MB
  float* H1 = (float*)alloc((size_t)B * H * 4);               // 32 MB
  float* H2 = (float*)alloc((size_t)B * H * 4);               // 32 MB
  float* ps  = (float*)alloc(128 * 512 * 4);                  // 256 KB
  float* ps2 = (float*)alloc(128 * 512 * 4);
  float* nmi = (float*)alloc(512 * 4);
  float* isd = (float*)alloc(512 * 4);

  // ---- prep: x-stats partials + coeff cvt in one dispatch ----
  prep_k<<<128 + 1024, 256, 0, stream>>>(c1, C1h, (size_t)H * IN * NB / 4,
                                         c2, C2h, (size_t)H * H * NB / 4,
                                         x, ps, ps2);
  stats_final_k<<<1, 256, 0, stream>>>(ps, ps2, 32, IN, B, nmi, isd);

  // ---- layer 1 (C=256, K=4096); epilogue emits H1 column partials ----
  kan_gemm_fused<<<dim3(B / 128, 4), 512, 0, stream>>>(x, nmi, isd, C1h, H1, ps, ps2, IN);
  stats_final_k<<<2, 256, 0, stream>>>(ps, ps2, 128, H, B, nmi, isd);

  // ---- layer 2 (C=512, K=8192); epilogue emits H2 column partials ----
  kan_gemm_fused<<<dim3(B / 128, 4), 512, 0, stream>>>(H1, nmi, isd, C2h, H2, ps, ps2, H);
  stats_final_k<<<2, 256, 0, stream>>>(ps, ps2, 128, H, B, nmi, isd);

  // ---- layer 3 + skip (normalize fused) ----
  layer3_k<<<B / 16, 256, 0, stream>>>(H2, nmi, isd, c3, x, sw, sb, out);
}

// Round 10
// 440.129 us; speedup vs baseline: 1.4951x; 1.0391x over previous
//
#include <hip/hip_runtime.h>
#include <cstdint>
#include <cstddef>

// ---------------- types ----------------
typedef __attribute__((ext_vector_type(8))) _Float16 half8;   // MFMA f16 A/B frag (4 VGPRs)
typedef __attribute__((ext_vector_type(4))) _Float16 half4;
typedef __attribute__((ext_vector_type(2))) __fp16   fp16x2;  // cvt_pkrtz result type
typedef __attribute__((ext_vector_type(4))) float    floatx4; // MFMA C/D frag

static constexpr int B_ROWS = 16384;
static constexpr int IN_DIM = 256;
static constexpr int H_DIM  = 512;
static constexpr int NB     = 16;

__device__ __forceinline__ float fast_tanh(float x) {
  float ax = fabsf(x);
  float e  = __expf(2.0f * ax);             // e >= 1, inf-safe
  float t  = 1.0f - 2.0f / (e + 1.0f);
  return copysignf(t, x);
}

// async global->LDS, 16B per lane; LDS dest must be wave-uniform base + lane*16
__device__ __forceinline__ void gld16(const void* g, void* l) {
  __builtin_amdgcn_global_load_lds(
      (const __attribute__((address_space(1))) unsigned int*)g,
      (__attribute__((address_space(3))) unsigned int*)l, 16, 0, 0);
}

// ---------------- prep: x column-stats partials (blocks 0..127) + coeff cvt (blocks 128+) ----
// cvt folds K_n = exp(-2 c_n^2) into the fp16 coeffs.
__global__ __launch_bounds__(256) void prep_k(const float* __restrict__ c1, _Float16* __restrict__ d1, size_t n41,
                                              const float* __restrict__ c2, _Float16* __restrict__ d2, size_t n42,
                                              const float* __restrict__ X,
                                              float* __restrict__ ps, float* __restrict__ ps2) {
  const int bx = blockIdx.x;
  if (bx < 128) {
    // ---- stats on X: cols=256 (4 col-groups of 64), 32 row-segs of 512 ----
    int c     = (bx & 3) * 64 + (threadIdx.x & 63);
    int chunk = threadIdx.x >> 6;
    int seg   = bx >> 2;
    int r0    = seg * 512;
    double s = 0.0, s2 = 0.0;
    for (int r = r0 + chunk; r < r0 + 512; r += 4) {
      float v = X[(size_t)r * IN_DIM + c];
      s += v; s2 += (double)v * (double)v;
    }
    __shared__ float Ls[256], Ls2[256];
    Ls[threadIdx.x] = (float)s; Ls2[threadIdx.x] = (float)s2;
    __syncthreads();
    if (chunk == 0) {
      int cl = threadIdx.x;
      float a  = Ls[cl]  + Ls[cl + 64]  + Ls[cl + 128]  + Ls[cl + 192];
      float b  = Ls2[cl] + Ls2[cl + 64] + Ls2[cl + 128] + Ls2[cl + 192];
      ps [(size_t)seg * IN_DIM + c] = a;
      ps2[(size_t)seg * IN_DIM + c] = b;
    }
  } else {
    // ---- coeff conversion, grid-stride over remaining blocks ----
    size_t tot = n41 + n42;
    int nb_blocks = gridDim.x - 128;
    for (size_t i = (size_t)(bx - 128) * 256 + threadIdx.x; i < tot;
         i += (size_t)nb_blocks * 256) {
      const float4* sp; half4* dp; size_t j;
      if (i < n41) { sp = (const float4*)c1; dp = (half4*)d1; j = i; }
      else         { sp = (const float4*)c2; dp = (half4*)d2; j = i - n41; }
      float4 v = sp[j];
      int nb = (int)((j << 2) & 15);
      half4 r;
      float e0 = -2.f + (float)(nb + 0) * (4.f / 15.f);
      float e1 = -2.f + (float)(nb + 1) * (4.f / 15.f);
      float e2 = -2.f + (float)(nb + 2) * (4.f / 15.f);
      float e3 = -2.f + (float)(nb + 3) * (4.f / 15.f);
      r[0] = (_Float16)(v.x * __expf(-2.f * e0 * e0));
      r[1] = (_Float16)(v.y * __expf(-2.f * e1 * e1));
      r[2] = (_Float16)(v.z * __expf(-2.f * e2 * e2));
      r[3] = (_Float16)(v.w * __expf(-2.f * e3 * e3));
      dp[j] = r;
    }
  }
}

// ---------------- stats finalize (float partials) ----------------
// Emits isd = 1/(sd+eps), nmi = -mu*isd, and the packed float2 (isd, nmi).
__global__ void stats_final_k(const float* __restrict__ ps,
                              const float* __restrict__ ps2,
                              int segs, int cols, int rows,
                              float* __restrict__ nmi, float* __restrict__ isd,
                              float2* __restrict__ snpk) {
  int c = blockIdx.x * blockDim.x + threadIdx.x;
  if (c >= cols) return;
  double s = 0.0, s2 = 0.0;
  for (int g = 0; g < segs; g++) { s += ps[(size_t)g * cols + c]; s2 += ps2[(size_t)g * cols + c]; }
  double mean = s / rows;
  double var  = (s2 - s * s / rows) / (rows - 1);   // ddof=1
  if (var < 0.0) var = 0.0;
  float sd = (float)sqrt(var);
  float iv = 1.0f / (sd + 1e-6f);
  float nm = -(float)mean * iv;
  isd[c] = iv;
  nmi[c] = nm;
  snpk[c] = make_float2(iv, nm);
}

// ---------------- fused normalize+expand+GEMM+tanh + column-stats partials ----------------
// H[b, o] = tanh( sum_k basis(xn[b, k/16])_[k%16] * Cb[o, k] ),  K = C*16
// 128x128 tile, BK=64, 512 threads, grid (128,4), 2 blocks/CU.
// R16: ROLE-ORDERED WAVE GROUPS. R9 post-mortem: MfmaUtil 40.5 = exact MFMA issue
// arithmetic (1242/3075 cyc), VALUBusy 40.7, LDS ~19% -> pipes sum to ~100% = they
// run SERIALLY. The barrier phase-locks all waves into the same sub-phase order.
// Fix: ksw=1 waves run the step body in a DIFFERENT order (expand VALU first, then
// frags+MFMA) vs ksw=0 (frags, MFMA, expand, MFMA) -> at any instant half the waves
// are on VALU while the other half are on LDS/MFMA. Same work, same barriers, same
// DMA->xv retire-chain (DMA issued first in both orders). ksw is wave-uniform ->
// s_cbranch, no exec-mask cost. Expand-first is safe: As[abuf^1] is dead after the
// step-(k-1) barrier. Also: stats packed as float2 (one 8B load per thread-step).
// R14/R15 kept: k-split wave grid (8 waves = 2m x 2n x 2k, kq = ksw*4+quad, 8 LDS
// reads/wave/step), single 80 KB LDS arena (well-defined aliasing), DMA tri-buffer +
// counted vmcnt (never drained in-loop), erow=tid&127 A-write banking (conflicts=0),
// packed f16 expansion, lgkm-only raw barriers, LDS k-split merge + epilogue.
__global__ __launch_bounds__(512, 4) void kan_gemm_fused(const float* __restrict__ X,   // [B, C]
                                                         const float2* __restrict__ snpk, // [C] (isd, -mu*isd)
                                                         const _Float16* __restrict__ Bm, // [512, C*16]
                                                         float* __restrict__ Hout,        // [B, 512]
                                                         float* __restrict__ psum,        // [128, 512]
                                                         float* __restrict__ psum2,       // [128, 512]
                                                         int C) {
  const int K = C << 4;
  const int steps = K >> 6;                 // BK = 64
  // ---- single LDS arena: [0,32K) = As (2 bufs), [32K,80K) = Bs (3 bufs);
  //      epilogue reuses [0,64K) as merge tiles + [64K,66K) as Rs. Well-defined.
  __shared__ __align__(16) unsigned char LDSB[81920];
  _Float16* const Asb = reinterpret_cast<_Float16*>(LDSB);           // 2 x 8192 halfs
  _Float16* const Bsb = reinterpret_cast<_Float16*>(LDSB + 32768);   // 3 x 8192 halfs
  const int tid  = threadIdx.x;
  const int w = tid >> 6, lane = tid & 63;
  const int wm = w & 1, wn = (w >> 1) & 1, ksw = w >> 2;  // 2x2 spatial, 2-way k-split
  const int lrow = lane & 15, quad = lane >> 4;
  const int row0 = blockIdx.x * 128;
  const int col0 = blockIdx.y * 128;
  const int kq = ksw * 4 + quad;            // this lane's kseg within BK=64

  // ---- B staging: buffer = 1024 chunks of 16B; thread owns chunks tid, tid+512.
  const int s_row = tid >> 3;               // 0..63
  const int s_sl  = tid & 7;
  const int s_seg = s_sl ^ ((s_row >> 1) & 7);
  const _Float16* gB = Bm + (size_t)(col0 + s_row) * K + s_seg * 8;

  // ---- A expansion: erow = tid&127 (consecutive lanes -> consecutive rows, conflict-free
  //      b128 writes), eh = tid>>7 (wave-uniform col slot 0..3). Step k: col 4k+eh.
  const int erow = tid & 127;
  const int eh   = tid >> 7;
  const float*  xp  = X    + (size_t)(row0 + erow) * C + eh;  // step k: xp[4k]
  const float2* snp = snpk + eh;                              // step k: snp[4k]

  floatx4 acc[4][4] = {};

  // packed expansion: h[n] = Wv * g^n; f32 anchors at n=0,8; packed-f16 *g^2 chain between.
  auto expand_store = [&](float xr, float2 sn, int bufi) {
    float xn = fminf(fmaxf(fmaf(xr, sn.x, sn.y), -3.f), 3.f);
    float Wv = __expf(fmaf(-2.f, xn, -8.f) * xn);
    float g  = __expf((16.f / 15.f) * xn);
    float g2 = g * g, g4 = g2 * g2, g8 = g4 * g4;
    fp16x2 gg = __builtin_amdgcn_cvt_pkrtz(g2, g2);
    union { fp16x2 q[4]; half8 v8; } u0, u1;
    u0.q[0] = __builtin_amdgcn_cvt_pkrtz(Wv, Wv * g);
    u0.q[1] = u0.q[0] * gg;
    u0.q[2] = u0.q[1] * gg;
    u0.q[3] = u0.q[2] * gg;
    float W8 = Wv * g8;
    u1.q[0] = __builtin_amdgcn_cvt_pkrtz(W8, W8 * g);
    u1.q[1] = u1.q[0] * gg;
    u1.q[2] = u1.q[1] * gg;
    u1.q[3] = u1.q[2] * gg;
    int ks0 = 2 * eh;
    *(half8*)&Asb[(size_t)bufi * 8192 + (size_t)(ks0 * 128 + erow) * 8]       = u0.v8;
    *(half8*)&Asb[(size_t)bufi * 8192 + (size_t)((ks0 + 1) * 128 + erow) * 8] = u1.v8;
  };

  // ---- prologue: DMA(0), DMA(1), expand(0); one-time vmcnt(0) drain ----
  float  x0  = xp[0];
  float2 sn0 = snp[0];
  gld16(gB, &Bsb[(size_t)tid * 8]);
  gld16(gB + (size_t)64 * K, &Bsb[(size_t)(tid + 512) * 8]);
  __builtin_amdgcn_sched_barrier(0);
  gld16(gB + 64, &Bsb[8192 + (size_t)tid * 8]);
  gld16(gB + 64 + (size_t)64 * K, &Bsb[8192 + (size_t)(tid + 512) * 8]);
  __builtin_amdgcn_sched_barrier(0);
  float  xv = xp[4];                         // regs for step-0's expand(1)
  float2 sv = snp[4];
  expand_store(x0, sn0, 0);
  asm volatile("s_waitcnt vmcnt(0)" ::: "memory");   // one-time: Bs[0], Bs[1] resident
  asm volatile("s_waitcnt lgkmcnt(0)" ::: "memory");
  __builtin_amdgcn_s_barrier();
  __builtin_amdgcn_sched_barrier(0);

  // ---- main loop: raw barrier per step, vmcnt never drained; role-ordered by ksw ----
  int bcur = 0;                                      // Bs buffer for step k
  for (int k = 0; k < steps; k++) {
    const int abuf = k & 1;
    const bool more  = (k + 1 < steps);
    const bool more2 = (k + 2 < steps);
    const int b2 = (bcur == 0) ? 2 : bcur - 1;       // (k+2)%3
    if (more2) {
      gld16(gB + (size_t)(k + 2) * 64, &Bsb[(size_t)b2 * 8192 + (size_t)tid * 8]);
      gld16(gB + (size_t)(k + 2) * 64 + (size_t)64 * K,
            &Bsb[(size_t)b2 * 8192 + (size_t)(tid + 512) * 8]);
      __builtin_amdgcn_sched_barrier(0);
    }
    half8 af[4], bf[4];
    auto read_frags = [&]() {
#pragma unroll
      for (int t = 0; t < 4; t++) {
        int arow = wm * 64 + t * 16 + lrow;
        af[t] = *(const half8*)&Asb[(size_t)abuf * 8192 + (size_t)(kq * 128 + arow) * 8];
      }
#pragma unroll
      for (int t = 0; t < 4; t++) {
        int brow = wn * 64 + t * 16 + lrow;
        int bchunk = brow * 8 + (kq ^ ((brow >> 1) & 7));
        bf[t] = *(const half8*)&Bsb[(size_t)bcur * 8192 + (size_t)bchunk * 8];
      }
    };
    auto do_expand = [&]() {
      if (more) {
        expand_store(xv, sv, abuf ^ 1);
        if (more2) {
          xv = xp[4 * (k + 2)];
          sv = snp[4 * (k + 2)];
        }
      }
    };
    if (ksw == 0) {
      // [frags -> MFMA half -> expand -> MFMA half]
      read_frags();
      __builtin_amdgcn_s_setprio(1);
#pragma unroll
      for (int tm = 0; tm < 2; tm++)
#pragma unroll
        for (int tn = 0; tn < 4; tn++)
          acc[tm][tn] = __builtin_amdgcn_mfma_f32_16x16x32_f16(af[tm], bf[tn], acc[tm][tn], 0, 0, 0);
      __builtin_amdgcn_s_setprio(0);
      do_expand();
      __builtin_amdgcn_s_setprio(1);
#pragma unroll
      for (int tm = 2; tm < 4; tm++)
#pragma unroll
        for (int tn = 0; tn < 4; tn++)
          acc[tm][tn] = __builtin_amdgcn_mfma_f32_16x16x32_f16(af[tm], bf[tn], acc[tm][tn], 0, 0, 0);
      __builtin_amdgcn_s_setprio(0);
    } else {
      // [expand -> frags -> MFMA all]: VALU first while ksw=0 waves hit LDS/MFMA
      do_expand();
      read_frags();
      __builtin_amdgcn_s_setprio(1);
#pragma unroll
      for (int tm = 0; tm < 4; tm++)
#pragma unroll
        for (int tn = 0; tn < 4; tn++)
          acc[tm][tn] = __builtin_amdgcn_mfma_f32_16x16x32_f16(af[tm], bf[tn], acc[tm][tn], 0, 0, 0);
      __builtin_amdgcn_s_setprio(0);
    }
    asm volatile("s_waitcnt lgkmcnt(0)" ::: "memory");   // LDS writes visible; NO vmcnt drain
    __builtin_amdgcn_s_barrier();
    __builtin_amdgcn_sched_barrier(0);
    bcur = (bcur == 2) ? 0 : bcur + 1;
  }

  // ---- k-split merge: ks=1 waves dump acc into the (dead) LDS arena; ks=0 adds ----
  float* MB = reinterpret_cast<float*>(LDSB);        // [0,64K): 4 tiles x 16 KB
  const int p = wm * 2 + wn;                         // spatial tile id 0..3
  asm volatile("s_waitcnt vmcnt(0)" ::: "memory");   // safety: all DMA landed (one-time)
  if (ksw == 1) {
    float* dst = MB + (size_t)p * 4096;
#pragma unroll
    for (int tm = 0; tm < 4; tm++)
#pragma unroll
      for (int tn = 0; tn < 4; tn++)
        *(floatx4*)&dst[((tm * 4 + tn) * 64 + lane) * 4] = acc[tm][tn];
  }
  asm volatile("s_waitcnt lgkmcnt(0)" ::: "memory");
  __builtin_amdgcn_s_barrier();
  __builtin_amdgcn_sched_barrier(0);

  // ---- epilogue on ks=0 waves: merge + tanh + store + column partial sums ----
  float* Rs1 = MB + 16384;                           // [64K,66K): [2][128] + [2][128]
  float* Rs2 = Rs1 + 256;
  if (ksw == 0) {
    const float* src = MB + (size_t)p * 4096;
    float s1[4] = {0.f, 0.f, 0.f, 0.f}, s2v[4] = {0.f, 0.f, 0.f, 0.f};
#pragma unroll
    for (int tm = 0; tm < 4; tm++) {
#pragma unroll
      for (int tn = 0; tn < 4; tn++) {
        floatx4 other = *(const floatx4*)&src[((tm * 4 + tn) * 64 + lane) * 4];
        int gcol = col0 + wn * 64 + tn * 16 + lrow;
#pragma unroll
        for (int r = 0; r < 4; r++) {
          int grow = row0 + wm * 64 + tm * 16 + quad * 4 + r;
          float v = fast_tanh(acc[tm][tn][r] + other[r]);
          Hout[(size_t)grow * H_DIM + gcol] = v;
          s1[tn] += v; s2v[tn] += v * v;
        }
      }
    }
#pragma unroll
    for (int tn = 0; tn < 4; tn++) {
      s1[tn]  += __shfl_xor(s1[tn], 16);  s1[tn]  += __shfl_xor(s1[tn], 32);
      s2v[tn] += __shfl_xor(s2v[tn], 16); s2v[tn] += __shfl_xor(s2v[tn], 32);
    }
    if (quad == 0) {
#pragma unroll
      for (int tn = 0; tn < 4; tn++) {
        Rs1[wm * 128 + wn * 64 + tn * 16 + lrow] = s1[tn];
        Rs2[wm * 128 + wn * 64 + tn * 16 + lrow] = s2v[tn];
      }
    }
  }
  asm volatile("s_waitcnt lgkmcnt(0)" ::: "memory");    // avoid draining Hout stores
  __builtin_amdgcn_s_barrier();
  __builtin_amdgcn_sched_barrier(0);
  if (tid < 128) {
    psum [(size_t)blockIdx.x * H_DIM + col0 + tid] = Rs1[tid] + Rs1[128 + tid];
    psum2[(size_t)blockIdx.x * H_DIM + col0 + tid] = Rs2[tid] + Rs2[128 + tid];
  }
}

// ---------------- layer 3 (out dim 1) + skip, fp32, normalize fused ----------------
__global__ __launch_bounds__(256) void layer3_k(const float* __restrict__ H2,
                                                const float* __restrict__ nmi,
                                                const float* __restrict__ isd,
                                                const float* __restrict__ C3,
                                                const float* __restrict__ X,
                                                const float* __restrict__ SW,
                                                const float* __restrict__ SB,
                                                float* __restrict__ OUT) {
  int w = threadIdx.x >> 6, lane = threadIdx.x & 63;
  float Kn[NB];
#pragma unroll
  for (int n = 0; n < NB; n++) {
    float c = -2.f + (float)n * (4.f / 15.f);
    Kn[n] = __expf(-2.f * c * c);
  }
  float sb0 = SB[0];
  int row_base = blockIdx.x * 16 + w * 4;
  for (int r = 0; r < 4; r++) {
    int row = row_base + r;
    float s = 0.f;
#pragma unroll
    for (int j = 0; j < 8; j++) {
      int i = lane + 64 * j;
      float hv = H2[(size_t)row * H_DIM + i];
      float xn = fminf(fmaxf(fmaf(hv, isd[i], nmi[i]), -3.f), 3.f);
      float Wf = __expf(fmaf(-2.f, xn, -8.f) * xn);
      float gf = __expf((16.f / 15.f) * xn);
      const floatx4* cp = (const floatx4*)(C3 + (size_t)i * NB);
      floatx4 c0 = cp[0], c1 = cp[1], c2 = cp[2], c3 = cp[3];
      float p = Wf;
#pragma unroll
      for (int n = 0; n < 4; n++) { s += p * Kn[n]      * c0[n]; p *= gf; }
#pragma unroll
      for (int n = 0; n < 4; n++) { s += p * Kn[n + 4]  * c1[n]; p *= gf; }
#pragma unroll
      for (int n = 0; n < 4; n++) { s += p * Kn[n + 8]  * c2[n]; p *= gf; }
#pragma unroll
      for (int n = 0; n < 4; n++) { s += p * Kn[n + 12] * c3[n]; p *= gf; }
    }
#pragma unroll
    for (int j = 0; j < 4; j++) {
      int i = lane + 64 * j;
      s += X[(size_t)row * IN_DIM + i] * SW[i];
    }
#pragma unroll
    for (int off = 32; off > 0; off >>= 1) s += __shfl_down(s, off);
    if (lane == 0) OUT[row] = s + sb0;
  }
}

// ---------------- launcher ----------------
extern "C" void kernel_launch(void* const* d_in, const int* in_sizes, int n_in,
                              void* d_out, int out_size, void* d_ws, size_t ws_size,
                              hipStream_t stream) {
  const float* x  = (const float*)d_in[0];   // [16384, 256]
  const float* c1 = (const float*)d_in[1];   // [512, 256, 16]
  const float* c2 = (const float*)d_in[2];   // [512, 512, 16]
  const float* c3 = (const float*)d_in[3];   // [1, 512, 16]
  const float* sw = (const float*)d_in[4];   // [1, 256]
  const float* sb = (const float*)d_in[5];   // [1]
  float* out = (float*)d_out;

  const int B = B_ROWS, IN = IN_DIM, H = H_DIM;

  char* ws = (char*)d_ws;
  size_t off = 0;
  auto alloc = [&](size_t bytes) -> void* {
    void* p = ws + off;
    off += (bytes + 255) & ~(size_t)255;
    return p;
  };
  _Float16* C1h = (_Float16*)alloc((size_t)H * IN * NB * 2);  //  4 MB
  _Float16* C2h = (_Float16*)alloc((size_t)H * H  * NB * 2);  //  8 MB
  float* H1 = (float*)alloc((size_t)B * H * 4);               // 32 MB
  float* H2 = (float*)alloc((size_t)B * H * 4);               // 32 MB
  float* ps  = (float*)alloc(128 * 512 * 4);                  // 256 KB
  float* ps2 = (float*)alloc(128 * 512 * 4);
  float* nmi = (float*)alloc(512 * 4);
  float* isd = (float*)alloc(512 * 4);
  float2* snpk = (float2*)alloc(512 * 8);

  // ---- prep: x-stats partials + coeff cvt in one dispatch ----
  prep_k<<<128 + 1024, 256, 0, stream>>>(c1, C1h, (size_t)H * IN * NB / 4,
                                         c2, C2h, (size_t)H * H * NB / 4,
                                         x, ps, ps2);
  stats_final_k<<<1, 256, 0, stream>>>(ps, ps2, 32, IN, B, nmi, isd, snpk);

  // ---- layer 1 (C=256, K=4096); epilogue emits H1 column partials ----
  kan_gemm_fused<<<dim3(B / 128, 4), 512, 0, stream>>>(x, snpk, C1h, H1, ps, ps2, IN);
  stats_final_k<<<2, 256, 0, stream>>>(ps, ps2, 128, H, B, nmi, isd, snpk);

  // ---- layer 2 (C=512, K=8192); epilogue emits H2 column partials ----
  kan_gemm_fused<<<dim3(B / 128, 4), 512, 0, stream>>>(H1, snpk, C2h, H2, ps, ps2, H);
  stats_final_k<<<2, 256, 0, stream>>>(ps, ps2, 128, H, B, nmi, isd, snpk);

  // ---- layer 3 + skip (normalize fused) ----
  layer3_k<<<B / 16, 256, 0, stream>>>(H2, nmi, isd, c3, x, sw, sb, out);
}